// Round 14
// baseline (119.290 us; speedup 1.0000x reference)
//
#include <hip/hip_runtime.h>
#include <hip/hip_bf16.h>
#include <math.h>

// bucket = 64 consecutive dst nodes. key packs (dlow<<17 | src), valid for n < 131072.
#define BSHIFT 6
#define BNODES 64
#define MAXB 1024   // max buckets supported by single-block scan (n <= 65536)
#define SORTCAP 4096

// ---------------- inline dtype detection: int64 vs int32 edge_index ----------------
__device__ __forceinline__ bool detect_f64(const void* edges, long long nn) {
    const long long* e64 = (const long long*)edges;
    bool ok = true;
#pragma unroll
    for (int i = 0; i < 8; ++i) {
        long long v = e64[i];
        ok = ok && (v >= 0 && v < nn);
    }
    return ok;
}

__device__ __forceinline__ float bf16lo(unsigned int u) {
    return __uint_as_float(u << 16);
}
__device__ __forceinline__ float bf16hi(unsigned int u) {
    return __uint_as_float(u & 0xFFFF0000u);
}
__device__ __forceinline__ float bf16dec(unsigned short u) {
    return __uint_as_float(((unsigned int)u) << 16);
}
__device__ __forceinline__ unsigned short bf16enc(float f) {
    __hip_bfloat16 h = __float2bfloat16(f);
    return *reinterpret_cast<unsigned short*>(&h);
}

// ---- (A) per-block-slice histogram -> partial[b*nblk + i] (plain stores) ----
__global__ __launch_bounds__(512) void k_hist(const void* edges, long long nn,
                                              long long E, long long epb,
                                              int nbuckets, int nblk, int* partial) {
    __shared__ int cnt[MAXB];
    int t = threadIdx.x;
    int i = blockIdx.x;
    for (int b = t; b < nbuckets; b += 512) cnt[b] = 0;
    __syncthreads();
    bool f64 = detect_f64(edges, nn);
    long long e0 = (long long)i * epb;
    long long e1 = e0 + epb; if (e1 > E) e1 = E;
    for (long long e = e0 + t; e < e1; e += 512) {
        int d = f64 ? (int)((const long long*)edges)[E + e] : ((const int*)edges)[E + e];
        atomicAdd(&cnt[d >> BSHIFT], 1);
    }
    __syncthreads();
    for (int b = t; b < nbuckets; b += 512) partial[b * nblk + i] = cnt[b];
}

// ---- (B) per-bucket exclusive scan over blocks (512-wide); emits bucket totals ----
__global__ __launch_bounds__(512) void k_scanB(int* partial, int nblk, int* totals) {
    __shared__ int tmp[512];
    int b = blockIdx.x, t = threadIdx.x;
    int v = (t < nblk) ? partial[b * nblk + t] : 0;
    tmp[t] = v;
    __syncthreads();
    for (int off = 1; off < 512; off <<= 1) {
        int a = (t >= off) ? tmp[t - off] : 0;
        __syncthreads();
        tmp[t] += a;
        __syncthreads();
    }
    if (t < nblk) partial[b * nblk + t] = tmp[t] - v;  // exclusive over blocks
    if (t == 511) totals[b] = tmp[511];
}

// ---- (C) bucket-level exclusive scan: base = exclusive(totals) ----
__global__ __launch_bounds__(1024) void k_scan(const int* __restrict__ totals, int nbuckets,
                                               int* base) {
    __shared__ int tmp[MAXB];
    int t = threadIdx.x;
    int v = (t < nbuckets) ? totals[t] : 0;
    tmp[t] = v;
    __syncthreads();
    for (int off = 1; off < MAXB; off <<= 1) {
        int a = (t >= off) ? tmp[t - off] : 0;
        __syncthreads();
        tmp[t] += a;
        __syncthreads();
    }
    if (t < nbuckets) base[t] = tmp[t] - v;
}

// ---- (D) place keys: LDS cursors seeded from base+partial; no global atomics ----
__global__ __launch_bounds__(512) void k_place(const void* edges, long long nn,
                                               long long E, long long epb,
                                               int nbuckets, int nblk,
                                               const int* __restrict__ base,
                                               const int* __restrict__ partial,
                                               unsigned int* keys) {
    __shared__ int cur[MAXB];
    int t = threadIdx.x;
    int i = blockIdx.x;
    for (int b = t; b < nbuckets; b += 512) cur[b] = base[b] + partial[b * nblk + i];
    __syncthreads();
    bool f64 = detect_f64(edges, nn);
    long long e0 = (long long)i * epb;
    long long e1 = e0 + epb; if (e1 > E) e1 = E;
    for (long long e = e0 + t; e < e1; e += 512) {
        int s, d;
        if (f64) {
            const long long* ee = (const long long*)edges;
            s = (int)ee[e]; d = (int)ee[E + e];
        } else {
            const int* ee = (const int*)edges;
            s = ee[e]; d = ee[E + e];
        }
        int pos = atomicAdd(&cur[d >> BSHIFT], 1);
        keys[pos] = (unsigned int)s | ((unsigned int)(d & (BNODES - 1)) << 17);
    }
}

// -------- per-bucket LDS counting sort -> node-exact CSR; fuses deg/dinv --------
__global__ __launch_bounds__(256) void k_sortdeg(unsigned int* keys,
                                                 const int* __restrict__ base,
                                                 const int* __restrict__ totals,
                                                 int* rowstart, int* counts,
                                                 float* dinv, int n,
                                                 unsigned int* scratch) {
    __shared__ unsigned int kbuf[SORTCAP];
    __shared__ int hist[BNODES];
    __shared__ int cur[BNODES];
    int t = threadIdx.x;
    int bk = blockIdx.x;
    int st = base[bk], c = totals[bk];
    if (t < BNODES) hist[t] = 0;
    __syncthreads();
    bool fits = (c <= SORTCAP);
    if (fits) {
        for (int i = t; i < c; i += 256) {
            unsigned int k = keys[st + i];
            kbuf[i] = k;
            atomicAdd(&hist[k >> 17], 1);
        }
    } else {  // statistically never for random edges; correct fallback via global scratch
        for (int i = t; i < c; i += 256) {
            unsigned int k = keys[st + i];
            scratch[st + i] = k;
            atomicAdd(&hist[k >> 17], 1);
        }
    }
    __syncthreads();
    if (t < 64) {  // wave 0: scan 64 counters
        int v = hist[t];
        int incl = v;
        for (int o = 1; o < 64; o <<= 1) {
            int other = __shfl_up(incl, o, 64);
            if (t >= o) incl += other;
        }
        int ex = incl - v;
        cur[t] = ex;
        int node = bk * BNODES + t;
        if (node < n) {
            rowstart[node] = st + ex;
            counts[node] = v;
            dinv[node] = rsqrtf((float)v + 1.0f);
        }
    }
    __syncthreads();
    if (fits) {
        for (int i = t; i < c; i += 256) {
            unsigned int k = kbuf[i];
            int pos = atomicAdd(&cur[k >> 17], 1);
            keys[st + pos] = k & 0x1FFFFu;
        }
    } else {
        for (int i = t; i < c; i += 256) {
            unsigned int k = scratch[st + i];
            int pos = atomicAdd(&cur[k >> 17], 1);
            keys[st + pos] = k & 0x1FFFFu;
        }
    }
}

// -------- GEMM1: h1b[n,64](bf16) = dinv * (x[n,64] @ W1[64,64]) --------
__global__ __launch_bounds__(256) void k_gemm1(const float* __restrict__ x,
                                               const float* __restrict__ W,
                                               const float* __restrict__ dinv,
                                               unsigned short* __restrict__ h) {
    __shared__ float Ws[64][64];
    __shared__ float xs[16][64];
    int t = threadIdx.x;
    for (int i = t; i < 64 * 64; i += 256) Ws[i >> 6][i & 63] = W[i];
    long long row0 = (long long)blockIdx.x * 16;
    ((float4*)xs)[t] = ((const float4*)(x + row0 * 64))[t];
    __syncthreads();
    int r = t >> 4, c0 = (t & 15) * 4;
    float4 acc = {0.f, 0.f, 0.f, 0.f};
#pragma unroll
    for (int k = 0; k < 64; ++k) {
        float xv = xs[r][k];
        float4 wv = *((const float4*)&Ws[k][c0]);
        acc.x += xv * wv.x; acc.y += xv * wv.y;
        acc.z += xv * wv.z; acc.w += xv * wv.w;
    }
    float di = dinv[row0 + r];
    ushort4 pk;
    pk.x = bf16enc(di * acc.x);
    pk.y = bf16enc(di * acc.y);
    pk.z = bf16enc(di * acc.z);
    pk.w = bf16enc(di * acc.w);
    *((ushort4*)(h + (row0 + r) * 64 + c0)) = pk;
}

// ------- CSR aggregation, 64 feats (bf16, 4-wide) + FUSED GEMM2 epilogue -------
// 16 lanes x uint2 (8B) cover a 128B row; quarter-waves process edges k+0..k+3.
// Unroll 16 -> 4 gathers in flight per lane. 32-bit indices -> saddr loads.
// Epilogue: relu'd row (4 feats/lane) -> 64x16 dot with LDS-staged W2 (stride 17).
__global__ __launch_bounds__(256) void k_agg64(const int* __restrict__ rowstart,
                                               const int* __restrict__ counts,
                                               const unsigned int* __restrict__ srcs,
                                               const uint2* __restrict__ hb4,
                                               const float* __restrict__ dinv,
                                               const float* __restrict__ b,
                                               const float* __restrict__ W2,
                                               unsigned short* __restrict__ h2b, int n) {
    __shared__ float W2s[64 * 17];
    int t = threadIdx.x;
    for (int i = t; i < 64 * 16; i += 256) W2s[(i >> 4) * 17 + (i & 15)] = W2[i];
    __syncthreads();  // before any divergence; all waves hit this immediately

    int d = (blockIdx.x * 256 + t) >> 6;
    if (d >= n) return;
    int lane = t & 63;
    unsigned int q = lane >> 4;      // quarter: edge offset 0..3
    unsigned int fl = lane & 15;     // feature-quad index (feats 4fl..4fl+3)
    float a0 = 0.f, a1 = 0.f, a2 = 0.f, a3 = 0.f;
    if (q == 0) {                    // self-loop counted once
        uint2 u = hb4[(unsigned int)d * 16u + fl];
        a0 = bf16lo(u.x); a1 = bf16hi(u.x); a2 = bf16lo(u.y); a3 = bf16hi(u.y);
    }
    int start = rowstart[d];
    int cnt = counts[d];
    int k = 0;
    for (; k + 16 <= cnt; k += 16) {
        unsigned int s0 = srcs[start + k + q];
        unsigned int s1 = srcs[start + k + 4 + q];
        unsigned int s2 = srcs[start + k + 8 + q];
        unsigned int s3 = srcs[start + k + 12 + q];
        uint2 u0 = hb4[s0 * 16u + fl];
        uint2 u1 = hb4[s1 * 16u + fl];
        uint2 u2 = hb4[s2 * 16u + fl];
        uint2 u3 = hb4[s3 * 16u + fl];
        a0 += bf16lo(u0.x); a1 += bf16hi(u0.x); a2 += bf16lo(u0.y); a3 += bf16hi(u0.y);
        a0 += bf16lo(u1.x); a1 += bf16hi(u1.x); a2 += bf16lo(u1.y); a3 += bf16hi(u1.y);
        a0 += bf16lo(u2.x); a1 += bf16hi(u2.x); a2 += bf16lo(u2.y); a3 += bf16hi(u2.y);
        a0 += bf16lo(u3.x); a1 += bf16hi(u3.x); a2 += bf16lo(u3.y); a3 += bf16hi(u3.y);
    }
    for (; k + 8 <= cnt; k += 8) {
        unsigned int s0 = srcs[start + k + q];
        unsigned int s1 = srcs[start + k + 4 + q];
        uint2 u0 = hb4[s0 * 16u + fl];
        uint2 u1 = hb4[s1 * 16u + fl];
        a0 += bf16lo(u0.x); a1 += bf16hi(u0.x); a2 += bf16lo(u0.y); a3 += bf16hi(u0.y);
        a0 += bf16lo(u1.x); a1 += bf16hi(u1.x); a2 += bf16lo(u1.y); a3 += bf16hi(u1.y);
    }
    for (; k < cnt; k += 4) {
        int idx = k + (int)q;
        if (idx < cnt) {
            uint2 u0 = hb4[srcs[start + idx] * 16u + fl];
            a0 += bf16lo(u0.x); a1 += bf16hi(u0.x); a2 += bf16lo(u0.y); a3 += bf16hi(u0.y);
        }
    }
    // combine quarters (lanes with equal fl: xor 16, 32); all lanes hold totals
    a0 += __shfl_xor(a0, 16); a0 += __shfl_xor(a0, 32);
    a1 += __shfl_xor(a1, 16); a1 += __shfl_xor(a1, 32);
    a2 += __shfl_xor(a2, 16); a2 += __shfl_xor(a2, 32);
    a3 += __shfl_xor(a3, 16); a3 += __shfl_xor(a3, 32);
    float di = dinv[d];
    float4 bb = ((const float4*)b)[fl];
    float o0 = fmaxf(di * a0 + bb.x, 0.f);   // relu'd feat 4fl+0
    float o1 = fmaxf(di * a1 + bb.y, 0.f);
    float o2 = fmaxf(di * a2 + bb.z, 0.f);
    float o3 = fmaxf(di * a3 + bb.w, 0.f);

    // fused GEMM2: lane computes partial dot for col c over its quarter's 16 feats
    int c = lane & 15;
    float acc = 0.f;
#pragma unroll
    for (int j = 0; j < 16; ++j) {
        int kk = (int)q * 16 + j;            // feat index this lane consumes
        int srcl = (int)q * 20 + (j >> 2);   // q*16 + (kk>>2): holder within quarter
        float fv;
        if ((j & 3) == 0)      fv = __shfl(o0, srcl);
        else if ((j & 3) == 1) fv = __shfl(o1, srcl);
        else if ((j & 3) == 2) fv = __shfl(o2, srcl);
        else                   fv = __shfl(o3, srcl);
        acc += fv * W2s[kk * 17 + c];
    }
    acc += __shfl_xor(acc, 16);
    acc += __shfl_xor(acc, 32);
    if (lane < 16) h2b[(unsigned int)d * 16u + c] = bf16enc(di * acc);
}

// ------- CSR aggregation, 16 feats (bf16, 4-wide) + fused log_softmax -----------
// 4 lanes x uint2 (8B) cover a 32B row; 4 edge-groups per 16-lane node group.
__global__ __launch_bounds__(256) void k_agg16(const int* __restrict__ rowstart,
                                               const int* __restrict__ counts,
                                               const unsigned int* __restrict__ srcs,
                                               const uint2* __restrict__ hb4,
                                               const float* __restrict__ dinv,
                                               const float* __restrict__ b,
                                               float* __restrict__ out, int n) {
    int g = (blockIdx.x * 256 + threadIdx.x) >> 4;
    if (g >= n) return;
    int lane = threadIdx.x & 15;
    unsigned int eg = lane >> 2;     // edge-group 0..3
    unsigned int fp = lane & 3;      // feature quad: feats 4fp..4fp+3
    float a0 = 0.f, a1 = 0.f, a2 = 0.f, a3 = 0.f;
    if (eg == 0) {
        uint2 u = hb4[(unsigned int)g * 4u + fp];
        a0 = bf16lo(u.x); a1 = bf16hi(u.x); a2 = bf16lo(u.y); a3 = bf16hi(u.y);
    }
    int start = rowstart[g];
    int cnt = counts[g];
    int k = 0;
    for (; k + 8 <= cnt; k += 8) {
        unsigned int s0 = srcs[start + k + eg];
        unsigned int s1 = srcs[start + k + 4 + eg];
        uint2 u0 = hb4[s0 * 4u + fp];
        uint2 u1 = hb4[s1 * 4u + fp];
        a0 += bf16lo(u0.x); a1 += bf16hi(u0.x); a2 += bf16lo(u0.y); a3 += bf16hi(u0.y);
        a0 += bf16lo(u1.x); a1 += bf16hi(u1.x); a2 += bf16lo(u1.y); a3 += bf16hi(u1.y);
    }
    for (; k < cnt; k += 4) {
        int idx = k + (int)eg;
        if (idx < cnt) {
            uint2 u0 = hb4[srcs[start + idx] * 4u + fp];
            a0 += bf16lo(u0.x); a1 += bf16hi(u0.x); a2 += bf16lo(u0.y); a3 += bf16hi(u0.y);
        }
    }
    // reduce across the 4 edge-groups (xor 4, 8 within the 16-lane group)
    a0 += __shfl_xor(a0, 4); a0 += __shfl_xor(a0, 8);
    a1 += __shfl_xor(a1, 4); a1 += __shfl_xor(a1, 8);
    a2 += __shfl_xor(a2, 4); a2 += __shfl_xor(a2, 8);
    a3 += __shfl_xor(a3, 4); a3 += __shfl_xor(a3, 8);
    float di = dinv[g];
    float4 bb = ((const float4*)b)[fp];
    float v0 = di * a0 + bb.x;
    float v1 = di * a1 + bb.y;
    float v2 = di * a2 + bb.z;
    float v3 = di * a3 + bb.w;
    // softmax across the 16 features (4 per lane x 4 fp-lanes: xor 1, 2)
    float m = fmaxf(fmaxf(v0, v1), fmaxf(v2, v3));
    m = fmaxf(m, __shfl_xor(m, 1));
    m = fmaxf(m, __shfl_xor(m, 2));
    float ex = __expf(v0 - m) + __expf(v1 - m) + __expf(v2 - m) + __expf(v3 - m);
    ex += __shfl_xor(ex, 1);
    ex += __shfl_xor(ex, 2);
    float lse = __logf(ex) + m;
    if (eg == 0) {
        float4 o4;
        o4.x = v0 - lse; o4.y = v1 - lse; o4.z = v2 - lse; o4.w = v3 - lse;
        ((float4*)(out + (unsigned int)g * 16u))[fp] = o4;
    }
}

extern "C" void kernel_launch(void* const* d_in, const int* in_sizes, int n_in,
                              void* d_out, int out_size, void* d_ws, size_t ws_size,
                              hipStream_t stream) {
    const float* x  = (const float*)d_in[0];
    const void*  ei = d_in[1];
    const float* W1 = (const float*)d_in[2];
    const float* b1 = (const float*)d_in[3];
    const float* W2 = (const float*)d_in[4];
    const float* b2 = (const float*)d_in[5];

    long long dh  = in_sizes[3];                 // 64
    long long din = in_sizes[2] / dh;            // 64
    long long n   = in_sizes[0] / din;           // 50000
    long long E   = (long long)in_sizes[1] / 2;  // 1.6M
    int nbuckets  = (int)((n + BNODES - 1) >> BSHIFT);  // 782

    // slice size: keep block count <= 512 (k_scanB width); more blocks = occupancy
    long long epb = 4096;
    while ((E + epb - 1) / epb > 512) epb <<= 1;
    int nblk = (int)((E + epb - 1) / epb);       // 391 for E=1.6M

    char* ws = (char*)d_ws;
    auto alloc = [&](size_t bytes) { void* p = ws; ws += (bytes + 255) & ~255ULL; return p; };
    int*   totals   = (int*)alloc(nbuckets * 4);
    int*   base     = (int*)alloc(nbuckets * 4);
    int*   rowstart = (int*)alloc(n * 4);
    int*   counts   = (int*)alloc(n * 4);
    float* dinv     = (float*)alloc(n * 4);
    int*   partial  = (int*)alloc((size_t)nbuckets * nblk * 4);
    unsigned int* keys = (unsigned int*)alloc(E * 4);
    unsigned short* h1b  = (unsigned short*)alloc(n * 64 * 2);
    unsigned short* h2b  = (unsigned short*)alloc(n * 16 * 2);
    // h1b is written only after sortdeg completes; before then its space doubles
    // as the (statistically never used) big-bucket sort scratch (E*4 <= n*64*2).
    unsigned int* sort_scratch = (unsigned int*)h1b;

    float* out = (float*)d_out;

    // binning: hist -> per-bucket block scan -> bucket scan -> place (no global atomics)
    k_hist<<<nblk, 512, 0, stream>>>(ei, n, E, epb, nbuckets, nblk, partial);
    k_scanB<<<nbuckets, 512, 0, stream>>>(partial, nblk, totals);
    k_scan<<<1, 1024, 0, stream>>>(totals, nbuckets, base);
    k_place<<<nblk, 512, 0, stream>>>(ei, n, E, epb, nbuckets, nblk, base, partial, keys);
    k_sortdeg<<<nbuckets, 256, 0, stream>>>(keys, base, totals, rowstart, counts,
                                            dinv, (int)n, sort_scratch);

    // layer 1 (+ fused layer-2 GEMM in agg64 epilogue)
    k_gemm1<<<(int)(n / 16), 256, 0, stream>>>(x, W1, dinv, h1b);
    k_agg64<<<(int)((n * 64 + 255) / 256), 256, 0, stream>>>(
        rowstart, counts, keys, (const uint2*)h1b, dinv, b1, W2, h2b, (int)n);

    // layer 2 aggregation + log_softmax
    k_agg16<<<(int)((n * 16 + 255) / 256), 256, 0, stream>>>(
        rowstart, counts, keys, (const uint2*)h2b, dinv, b2, out, (int)n);
}

// Round 15
// 114.551 us; speedup vs baseline: 1.0414x; 1.0414x over previous
//
#include <hip/hip_runtime.h>
#include <hip/hip_bf16.h>
#include <math.h>

// bucket = 64 consecutive dst nodes. key packs (dlow<<17 | src), valid for n < 131072.
#define BSHIFT 6
#define BNODES 64
#define MAXB 1024   // max buckets supported by single-block scan (n <= 65536)
#define SORTCAP 4096

// ---------------- inline dtype detection: int64 vs int32 edge_index ----------------
__device__ __forceinline__ bool detect_f64(const void* edges, long long nn) {
    const long long* e64 = (const long long*)edges;
    bool ok = true;
#pragma unroll
    for (int i = 0; i < 8; ++i) {
        long long v = e64[i];
        ok = ok && (v >= 0 && v < nn);
    }
    return ok;
}

__device__ __forceinline__ float bf16lo(unsigned int u) {
    return __uint_as_float(u << 16);
}
__device__ __forceinline__ float bf16hi(unsigned int u) {
    return __uint_as_float(u & 0xFFFF0000u);
}
__device__ __forceinline__ float bf16dec(unsigned short u) {
    return __uint_as_float(((unsigned int)u) << 16);
}
__device__ __forceinline__ unsigned short bf16enc(float f) {
    __hip_bfloat16 h = __float2bfloat16(f);
    return *reinterpret_cast<unsigned short*>(&h);
}

// ---- (A) per-block-slice histogram -> partial[b*nblk + i] (plain stores) ----
__global__ __launch_bounds__(512) void k_hist(const void* edges, long long nn,
                                              long long E, long long epb,
                                              int nbuckets, int nblk, int* partial) {
    __shared__ int cnt[MAXB];
    int t = threadIdx.x;
    int i = blockIdx.x;
    for (int b = t; b < nbuckets; b += 512) cnt[b] = 0;
    __syncthreads();
    bool f64 = detect_f64(edges, nn);
    long long e0 = (long long)i * epb;
    long long e1 = e0 + epb; if (e1 > E) e1 = E;
    for (long long e = e0 + t; e < e1; e += 512) {
        int d = f64 ? (int)((const long long*)edges)[E + e] : ((const int*)edges)[E + e];
        atomicAdd(&cnt[d >> BSHIFT], 1);
    }
    __syncthreads();
    for (int b = t; b < nbuckets; b += 512) partial[b * nblk + i] = cnt[b];
}

// ---- (B) per-bucket exclusive scan over blocks; emits bucket totals ----
__global__ __launch_bounds__(256) void k_scanB(int* partial, int nblk, int* totals) {
    __shared__ int tmp[256];
    int b = blockIdx.x, t = threadIdx.x;
    int v = (t < nblk) ? partial[b * nblk + t] : 0;
    tmp[t] = v;
    __syncthreads();
    for (int off = 1; off < 256; off <<= 1) {
        int a = (t >= off) ? tmp[t - off] : 0;
        __syncthreads();
        tmp[t] += a;
        __syncthreads();
    }
    if (t < nblk) partial[b * nblk + t] = tmp[t] - v;  // exclusive over blocks
    if (t == 255) totals[b] = tmp[255];
}

// ---- (C) bucket-level exclusive scan: base = exclusive(totals) ----
__global__ __launch_bounds__(1024) void k_scan(const int* __restrict__ totals, int nbuckets,
                                               int* base) {
    __shared__ int tmp[MAXB];
    int t = threadIdx.x;
    int v = (t < nbuckets) ? totals[t] : 0;
    tmp[t] = v;
    __syncthreads();
    for (int off = 1; off < MAXB; off <<= 1) {
        int a = (t >= off) ? tmp[t - off] : 0;
        __syncthreads();
        tmp[t] += a;
        __syncthreads();
    }
    if (t < nbuckets) base[t] = tmp[t] - v;
}

// ---- (D) place keys: LDS cursors seeded from base+partial; no global atomics ----
__global__ __launch_bounds__(512) void k_place(const void* edges, long long nn,
                                               long long E, long long epb,
                                               int nbuckets, int nblk,
                                               const int* __restrict__ base,
                                               const int* __restrict__ partial,
                                               unsigned int* keys) {
    __shared__ int cur[MAXB];
    int t = threadIdx.x;
    int i = blockIdx.x;
    for (int b = t; b < nbuckets; b += 512) cur[b] = base[b] + partial[b * nblk + i];
    __syncthreads();
    bool f64 = detect_f64(edges, nn);
    long long e0 = (long long)i * epb;
    long long e1 = e0 + epb; if (e1 > E) e1 = E;
    for (long long e = e0 + t; e < e1; e += 512) {
        int s, d;
        if (f64) {
            const long long* ee = (const long long*)edges;
            s = (int)ee[e]; d = (int)ee[E + e];
        } else {
            const int* ee = (const int*)edges;
            s = ee[e]; d = ee[E + e];
        }
        int pos = atomicAdd(&cur[d >> BSHIFT], 1);
        keys[pos] = (unsigned int)s | ((unsigned int)(d & (BNODES - 1)) << 17);
    }
}

// -------- per-bucket LDS counting sort -> node-exact CSR; fuses deg/dinv --------
__global__ __launch_bounds__(256) void k_sortdeg(unsigned int* keys,
                                                 const int* __restrict__ base,
                                                 const int* __restrict__ totals,
                                                 int* rowstart, int* counts,
                                                 float* dinv, int n,
                                                 unsigned int* scratch) {
    __shared__ unsigned int kbuf[SORTCAP];
    __shared__ int hist[BNODES];
    __shared__ int cur[BNODES];
    int t = threadIdx.x;
    int bk = blockIdx.x;
    int st = base[bk], c = totals[bk];
    if (t < BNODES) hist[t] = 0;
    __syncthreads();
    bool fits = (c <= SORTCAP);
    if (fits) {
        for (int i = t; i < c; i += 256) {
            unsigned int k = keys[st + i];
            kbuf[i] = k;
            atomicAdd(&hist[k >> 17], 1);
        }
    } else {  // statistically never for random edges; correct fallback via global scratch
        for (int i = t; i < c; i += 256) {
            unsigned int k = keys[st + i];
            scratch[st + i] = k;
            atomicAdd(&hist[k >> 17], 1);
        }
    }
    __syncthreads();
    if (t < 64) {  // wave 0: scan 64 counters
        int v = hist[t];
        int incl = v;
        for (int o = 1; o < 64; o <<= 1) {
            int other = __shfl_up(incl, o, 64);
            if (t >= o) incl += other;
        }
        int ex = incl - v;
        cur[t] = ex;
        int node = bk * BNODES + t;
        if (node < n) {
            rowstart[node] = st + ex;
            counts[node] = v;
            dinv[node] = rsqrtf((float)v + 1.0f);
        }
    }
    __syncthreads();
    if (fits) {
        for (int i = t; i < c; i += 256) {
            unsigned int k = kbuf[i];
            int pos = atomicAdd(&cur[k >> 17], 1);
            keys[st + pos] = k & 0x1FFFFu;
        }
    } else {
        for (int i = t; i < c; i += 256) {
            unsigned int k = scratch[st + i];
            int pos = atomicAdd(&cur[k >> 17], 1);
            keys[st + pos] = k & 0x1FFFFu;
        }
    }
}

// -------- GEMM1: h1b[n,64](bf16) = dinv * (x[n,64] @ W1[64,64]) --------
__global__ __launch_bounds__(256) void k_gemm1(const float* __restrict__ x,
                                               const float* __restrict__ W,
                                               const float* __restrict__ dinv,
                                               unsigned short* __restrict__ h) {
    __shared__ float Ws[64][64];
    __shared__ float xs[16][64];
    int t = threadIdx.x;
    for (int i = t; i < 64 * 64; i += 256) Ws[i >> 6][i & 63] = W[i];
    long long row0 = (long long)blockIdx.x * 16;
    ((float4*)xs)[t] = ((const float4*)(x + row0 * 64))[t];
    __syncthreads();
    int r = t >> 4, c0 = (t & 15) * 4;
    float4 acc = {0.f, 0.f, 0.f, 0.f};
#pragma unroll
    for (int k = 0; k < 64; ++k) {
        float xv = xs[r][k];
        float4 wv = *((const float4*)&Ws[k][c0]);
        acc.x += xv * wv.x; acc.y += xv * wv.y;
        acc.z += xv * wv.z; acc.w += xv * wv.w;
    }
    float di = dinv[row0 + r];
    ushort4 pk;
    pk.x = bf16enc(di * acc.x);
    pk.y = bf16enc(di * acc.y);
    pk.z = bf16enc(di * acc.z);
    pk.w = bf16enc(di * acc.w);
    *((ushort4*)(h + (row0 + r) * 64 + c0)) = pk;
}

// ------- CSR aggregation, 64 feats (bf16, 4-wide, 8 gathers in flight) + FUSED GEMM2 -------
// 16 lanes x uint2 (8B) cover a 128B row; quarter-waves process edges k+0..k+3.
// Unroll 32 -> 8 gathers in flight per lane (MLP probe vs r14's 4).
__global__ __launch_bounds__(256) void k_agg64(const int* __restrict__ rowstart,
                                               const int* __restrict__ counts,
                                               const unsigned int* __restrict__ srcs,
                                               const uint2* __restrict__ hb4,
                                               const float* __restrict__ dinv,
                                               const float* __restrict__ b,
                                               const float* __restrict__ W2,
                                               unsigned short* __restrict__ h2b, int n) {
    __shared__ float W2s[64 * 17];
    int t = threadIdx.x;
    for (int i = t; i < 64 * 16; i += 256) W2s[(i >> 4) * 17 + (i & 15)] = W2[i];
    __syncthreads();  // before any divergence; all waves hit this immediately

    int d = (blockIdx.x * 256 + t) >> 6;
    if (d >= n) return;
    int lane = t & 63;
    unsigned int q = lane >> 4;      // quarter: edge offset 0..3
    unsigned int fl = lane & 15;     // feature-quad index (feats 4fl..4fl+3)
    float a0 = 0.f, a1 = 0.f, a2 = 0.f, a3 = 0.f;
    if (q == 0) {                    // self-loop counted once
        uint2 u = hb4[(unsigned int)d * 16u + fl];
        a0 = bf16lo(u.x); a1 = bf16hi(u.x); a2 = bf16lo(u.y); a3 = bf16hi(u.y);
    }
    int start = rowstart[d];
    int cnt = counts[d];
    int k = 0;
    for (; k + 32 <= cnt; k += 32) {
        unsigned int s0 = srcs[start + k + q];
        unsigned int s1 = srcs[start + k + 4 + q];
        unsigned int s2 = srcs[start + k + 8 + q];
        unsigned int s3 = srcs[start + k + 12 + q];
        unsigned int s4 = srcs[start + k + 16 + q];
        unsigned int s5 = srcs[start + k + 20 + q];
        unsigned int s6 = srcs[start + k + 24 + q];
        unsigned int s7 = srcs[start + k + 28 + q];
        uint2 u0 = hb4[s0 * 16u + fl];
        uint2 u1 = hb4[s1 * 16u + fl];
        uint2 u2 = hb4[s2 * 16u + fl];
        uint2 u3 = hb4[s3 * 16u + fl];
        uint2 u4 = hb4[s4 * 16u + fl];
        uint2 u5 = hb4[s5 * 16u + fl];
        uint2 u6 = hb4[s6 * 16u + fl];
        uint2 u7 = hb4[s7 * 16u + fl];
        a0 += bf16lo(u0.x); a1 += bf16hi(u0.x); a2 += bf16lo(u0.y); a3 += bf16hi(u0.y);
        a0 += bf16lo(u1.x); a1 += bf16hi(u1.x); a2 += bf16lo(u1.y); a3 += bf16hi(u1.y);
        a0 += bf16lo(u2.x); a1 += bf16hi(u2.x); a2 += bf16lo(u2.y); a3 += bf16hi(u2.y);
        a0 += bf16lo(u3.x); a1 += bf16hi(u3.x); a2 += bf16lo(u3.y); a3 += bf16hi(u3.y);
        a0 += bf16lo(u4.x); a1 += bf16hi(u4.x); a2 += bf16lo(u4.y); a3 += bf16hi(u4.y);
        a0 += bf16lo(u5.x); a1 += bf16hi(u5.x); a2 += bf16lo(u5.y); a3 += bf16hi(u5.y);
        a0 += bf16lo(u6.x); a1 += bf16hi(u6.x); a2 += bf16lo(u6.y); a3 += bf16hi(u6.y);
        a0 += bf16lo(u7.x); a1 += bf16hi(u7.x); a2 += bf16lo(u7.y); a3 += bf16hi(u7.y);
    }
    for (; k + 16 <= cnt; k += 16) {
        unsigned int s0 = srcs[start + k + q];
        unsigned int s1 = srcs[start + k + 4 + q];
        unsigned int s2 = srcs[start + k + 8 + q];
        unsigned int s3 = srcs[start + k + 12 + q];
        uint2 u0 = hb4[s0 * 16u + fl];
        uint2 u1 = hb4[s1 * 16u + fl];
        uint2 u2 = hb4[s2 * 16u + fl];
        uint2 u3 = hb4[s3 * 16u + fl];
        a0 += bf16lo(u0.x); a1 += bf16hi(u0.x); a2 += bf16lo(u0.y); a3 += bf16hi(u0.y);
        a0 += bf16lo(u1.x); a1 += bf16hi(u1.x); a2 += bf16lo(u1.y); a3 += bf16hi(u1.y);
        a0 += bf16lo(u2.x); a1 += bf16hi(u2.x); a2 += bf16lo(u2.y); a3 += bf16hi(u2.y);
        a0 += bf16lo(u3.x); a1 += bf16hi(u3.x); a2 += bf16lo(u3.y); a3 += bf16hi(u3.y);
    }
    for (; k + 8 <= cnt; k += 8) {
        unsigned int s0 = srcs[start + k + q];
        unsigned int s1 = srcs[start + k + 4 + q];
        uint2 u0 = hb4[s0 * 16u + fl];
        uint2 u1 = hb4[s1 * 16u + fl];
        a0 += bf16lo(u0.x); a1 += bf16hi(u0.x); a2 += bf16lo(u0.y); a3 += bf16hi(u0.y);
        a0 += bf16lo(u1.x); a1 += bf16hi(u1.x); a2 += bf16lo(u1.y); a3 += bf16hi(u1.y);
    }
    for (; k < cnt; k += 4) {
        int idx = k + (int)q;
        if (idx < cnt) {
            uint2 u0 = hb4[srcs[start + idx] * 16u + fl];
            a0 += bf16lo(u0.x); a1 += bf16hi(u0.x); a2 += bf16lo(u0.y); a3 += bf16hi(u0.y);
        }
    }
    // combine quarters (lanes with equal fl: xor 16, 32); all lanes hold totals
    a0 += __shfl_xor(a0, 16); a0 += __shfl_xor(a0, 32);
    a1 += __shfl_xor(a1, 16); a1 += __shfl_xor(a1, 32);
    a2 += __shfl_xor(a2, 16); a2 += __shfl_xor(a2, 32);
    a3 += __shfl_xor(a3, 16); a3 += __shfl_xor(a3, 32);
    float di = dinv[d];
    float4 bb = ((const float4*)b)[fl];
    float o0 = fmaxf(di * a0 + bb.x, 0.f);   // relu'd feat 4fl+0
    float o1 = fmaxf(di * a1 + bb.y, 0.f);
    float o2 = fmaxf(di * a2 + bb.z, 0.f);
    float o3 = fmaxf(di * a3 + bb.w, 0.f);

    // fused GEMM2: lane computes partial dot for col c over its quarter's 16 feats
    int c = lane & 15;
    float acc = 0.f;
#pragma unroll
    for (int j = 0; j < 16; ++j) {
        int kk = (int)q * 16 + j;            // feat index this lane consumes
        int srcl = (int)q * 20 + (j >> 2);   // q*16 + (kk>>2): holder within quarter
        float fv;
        if ((j & 3) == 0)      fv = __shfl(o0, srcl);
        else if ((j & 3) == 1) fv = __shfl(o1, srcl);
        else if ((j & 3) == 2) fv = __shfl(o2, srcl);
        else                   fv = __shfl(o3, srcl);
        acc += fv * W2s[kk * 17 + c];
    }
    acc += __shfl_xor(acc, 16);
    acc += __shfl_xor(acc, 32);
    if (lane < 16) h2b[(unsigned int)d * 16u + c] = bf16enc(di * acc);
}

// ------- CSR aggregation, 16 feats (bf16 h, scalar 8-unroll) + fused log_softmax ----
__global__ __launch_bounds__(256) void k_agg16(const int* __restrict__ rowstart,
                                               const int* __restrict__ counts,
                                               const unsigned int* __restrict__ srcs,
                                               const unsigned short* __restrict__ hb,
                                               const float* __restrict__ dinv,
                                               const float* __restrict__ b,
                                               float* __restrict__ out, int n) {
    int g = (blockIdx.x * 256 + threadIdx.x) >> 4;
    if (g >= n) return;
    unsigned int f = threadIdx.x & 15;
    float acc = bf16dec(hb[(unsigned int)g * 16u + f]);
    int start = rowstart[g];
    int cnt = counts[g];
    int k = 0;
    for (; k + 8 <= cnt; k += 8) {
        unsigned int s0 = srcs[start + k];
        unsigned int s1 = srcs[start + k + 1];
        unsigned int s2 = srcs[start + k + 2];
        unsigned int s3 = srcs[start + k + 3];
        unsigned int s4 = srcs[start + k + 4];
        unsigned int s5 = srcs[start + k + 5];
        unsigned int s6 = srcs[start + k + 6];
        unsigned int s7 = srcs[start + k + 7];
        unsigned short u0 = hb[s0 * 16u + f];
        unsigned short u1 = hb[s1 * 16u + f];
        unsigned short u2 = hb[s2 * 16u + f];
        unsigned short u3 = hb[s3 * 16u + f];
        unsigned short u4 = hb[s4 * 16u + f];
        unsigned short u5 = hb[s5 * 16u + f];
        unsigned short u6 = hb[s6 * 16u + f];
        unsigned short u7 = hb[s7 * 16u + f];
        acc += bf16dec(u0); acc += bf16dec(u1); acc += bf16dec(u2); acc += bf16dec(u3);
        acc += bf16dec(u4); acc += bf16dec(u5); acc += bf16dec(u6); acc += bf16dec(u7);
    }
    for (; k < cnt; ++k) acc += bf16dec(hb[srcs[start + k] * 16u + f]);
    float v = dinv[g] * acc + b[f];
    float m = v;
#pragma unroll
    for (int o = 8; o >= 1; o >>= 1) m = fmaxf(m, __shfl_xor(m, o, 16));
    float ex = __expf(v - m);
#pragma unroll
    for (int o = 8; o >= 1; o >>= 1) ex += __shfl_xor(ex, o, 16);
    out[(unsigned int)g * 16u + f] = (v - m) - __logf(ex);
}

extern "C" void kernel_launch(void* const* d_in, const int* in_sizes, int n_in,
                              void* d_out, int out_size, void* d_ws, size_t ws_size,
                              hipStream_t stream) {
    const float* x  = (const float*)d_in[0];
    const void*  ei = d_in[1];
    const float* W1 = (const float*)d_in[2];
    const float* b1 = (const float*)d_in[3];
    const float* W2 = (const float*)d_in[4];
    const float* b2 = (const float*)d_in[5];

    long long dh  = in_sizes[3];                 // 64
    long long din = in_sizes[2] / dh;            // 64
    long long n   = in_sizes[0] / din;           // 50000
    long long E   = (long long)in_sizes[1] / 2;  // 1.6M
    int nbuckets  = (int)((n + BNODES - 1) >> BSHIFT);  // 782

    // slice size: 512 threads x ~16 edges; keep block count <= 256 (k_scanB width)
    long long epb = 8192;
    while ((E + epb - 1) / epb > 256) epb <<= 1;
    int nblk = (int)((E + epb - 1) / epb);       // 196 for E=1.6M

    char* ws = (char*)d_ws;
    auto alloc = [&](size_t bytes) { void* p = ws; ws += (bytes + 255) & ~255ULL; return p; };
    int*   totals   = (int*)alloc(nbuckets * 4);
    int*   base     = (int*)alloc(nbuckets * 4);
    int*   rowstart = (int*)alloc(n * 4);
    int*   counts   = (int*)alloc(n * 4);
    float* dinv     = (float*)alloc(n * 4);
    int*   partial  = (int*)alloc((size_t)nbuckets * nblk * 4);
    unsigned int* keys = (unsigned int*)alloc(E * 4);
    unsigned short* h1b  = (unsigned short*)alloc(n * 64 * 2);
    unsigned short* h2b  = (unsigned short*)alloc(n * 16 * 2);
    // h1b is written only after sortdeg completes; before then its space doubles
    // as the (statistically never used) big-bucket sort scratch (E*4 <= n*64*2).
    unsigned int* sort_scratch = (unsigned int*)h1b;

    float* out = (float*)d_out;

    // binning: hist -> per-bucket block scan -> bucket scan -> place (no global atomics)
    k_hist<<<nblk, 512, 0, stream>>>(ei, n, E, epb, nbuckets, nblk, partial);
    k_scanB<<<nbuckets, 256, 0, stream>>>(partial, nblk, totals);
    k_scan<<<1, 1024, 0, stream>>>(totals, nbuckets, base);
    k_place<<<nblk, 512, 0, stream>>>(ei, n, E, epb, nbuckets, nblk, base, partial, keys);
    k_sortdeg<<<nbuckets, 256, 0, stream>>>(keys, base, totals, rowstart, counts,
                                            dinv, (int)n, sort_scratch);

    // layer 1 (+ fused layer-2 GEMM in agg64 epilogue)
    k_gemm1<<<(int)(n / 16), 256, 0, stream>>>(x, W1, dinv, h1b);
    k_agg64<<<(int)((n * 64 + 255) / 256), 256, 0, stream>>>(
        rowstart, counts, keys, (const uint2*)h1b, dinv, b1, W2, h2b, (int)n);

    // layer 2 aggregation + log_softmax
    k_agg16<<<(int)((n * 16 + 255) / 256), 256, 0, stream>>>(
        rowstart, counts, keys, h2b, dinv, b2, out, (int)n);
}

// Round 16
// 114.468 us; speedup vs baseline: 1.0421x; 1.0007x over previous
//
#include <hip/hip_runtime.h>
#include <hip/hip_bf16.h>
#include <math.h>

// bucket = 64 consecutive dst nodes. key packs (dlow<<17 | src), valid for n < 131072.
#define BSHIFT 6
#define BNODES 64
#define MAXB 1024   // max buckets supported by single-block scan (n <= 65536)
#define SORTCAP 4096

// ---------------- inline dtype detection: int64 vs int32 edge_index ----------------
__device__ __forceinline__ bool detect_f64(const void* edges, long long nn) {
    const long long* e64 = (const long long*)edges;
    bool ok = true;
#pragma unroll
    for (int i = 0; i < 8; ++i) {
        long long v = e64[i];
        ok = ok && (v >= 0 && v < nn);
    }
    return ok;
}

__device__ __forceinline__ float bf16lo(unsigned int u) {
    return __uint_as_float(u << 16);
}
__device__ __forceinline__ float bf16hi(unsigned int u) {
    return __uint_as_float(u & 0xFFFF0000u);
}
__device__ __forceinline__ float bf16dec(unsigned short u) {
    return __uint_as_float(((unsigned int)u) << 16);
}
__device__ __forceinline__ unsigned short bf16enc(float f) {
    __hip_bfloat16 h = __float2bfloat16(f);
    return *reinterpret_cast<unsigned short*>(&h);
}

// ---- (A) per-block-slice histogram -> partial[b*nblk + i] (plain stores) ----
__global__ __launch_bounds__(512) void k_hist(const void* edges, long long nn,
                                              long long E, long long epb,
                                              int nbuckets, int nblk, int* partial) {
    __shared__ int cnt[MAXB];
    int t = threadIdx.x;
    int i = blockIdx.x;
    for (int b = t; b < nbuckets; b += 512) cnt[b] = 0;
    __syncthreads();
    bool f64 = detect_f64(edges, nn);
    long long e0 = (long long)i * epb;
    long long e1 = e0 + epb; if (e1 > E) e1 = E;
    for (long long e = e0 + t; e < e1; e += 512) {
        int d = f64 ? (int)((const long long*)edges)[E + e] : ((const int*)edges)[E + e];
        atomicAdd(&cnt[d >> BSHIFT], 1);
    }
    __syncthreads();
    for (int b = t; b < nbuckets; b += 512) partial[b * nblk + i] = cnt[b];
}

// ---- (B) per-bucket exclusive scan over blocks; emits bucket totals ----
__global__ __launch_bounds__(256) void k_scanB(int* partial, int nblk, int* totals) {
    __shared__ int tmp[256];
    int b = blockIdx.x, t = threadIdx.x;
    int v = (t < nblk) ? partial[b * nblk + t] : 0;
    tmp[t] = v;
    __syncthreads();
    for (int off = 1; off < 256; off <<= 1) {
        int a = (t >= off) ? tmp[t - off] : 0;
        __syncthreads();
        tmp[t] += a;
        __syncthreads();
    }
    if (t < nblk) partial[b * nblk + t] = tmp[t] - v;  // exclusive over blocks
    if (t == 255) totals[b] = tmp[255];
}

// ---- (C) bucket-level exclusive scan: base = exclusive(totals) ----
__global__ __launch_bounds__(1024) void k_scan(const int* __restrict__ totals, int nbuckets,
                                               int* base) {
    __shared__ int tmp[MAXB];
    int t = threadIdx.x;
    int v = (t < nbuckets) ? totals[t] : 0;
    tmp[t] = v;
    __syncthreads();
    for (int off = 1; off < MAXB; off <<= 1) {
        int a = (t >= off) ? tmp[t - off] : 0;
        __syncthreads();
        tmp[t] += a;
        __syncthreads();
    }
    if (t < nbuckets) base[t] = tmp[t] - v;
}

// ---- (D) place keys: LDS cursors seeded from base+partial; no global atomics ----
__global__ __launch_bounds__(512) void k_place(const void* edges, long long nn,
                                               long long E, long long epb,
                                               int nbuckets, int nblk,
                                               const int* __restrict__ base,
                                               const int* __restrict__ partial,
                                               unsigned int* keys) {
    __shared__ int cur[MAXB];
    int t = threadIdx.x;
    int i = blockIdx.x;
    for (int b = t; b < nbuckets; b += 512) cur[b] = base[b] + partial[b * nblk + i];
    __syncthreads();
    bool f64 = detect_f64(edges, nn);
    long long e0 = (long long)i * epb;
    long long e1 = e0 + epb; if (e1 > E) e1 = E;
    for (long long e = e0 + t; e < e1; e += 512) {
        int s, d;
        if (f64) {
            const long long* ee = (const long long*)edges;
            s = (int)ee[e]; d = (int)ee[E + e];
        } else {
            const int* ee = (const int*)edges;
            s = ee[e]; d = ee[E + e];
        }
        int pos = atomicAdd(&cur[d >> BSHIFT], 1);
        keys[pos] = (unsigned int)s | ((unsigned int)(d & (BNODES - 1)) << 17);
    }
}

// -------- per-bucket LDS counting sort -> node-exact CSR; fuses deg/dinv --------
__global__ __launch_bounds__(256) void k_sortdeg(unsigned int* keys,
                                                 const int* __restrict__ base,
                                                 const int* __restrict__ totals,
                                                 int* rowstart, int* counts,
                                                 float* dinv, int n,
                                                 unsigned int* scratch) {
    __shared__ unsigned int kbuf[SORTCAP];
    __shared__ int hist[BNODES];
    __shared__ int cur[BNODES];
    int t = threadIdx.x;
    int bk = blockIdx.x;
    int st = base[bk], c = totals[bk];
    if (t < BNODES) hist[t] = 0;
    __syncthreads();
    bool fits = (c <= SORTCAP);
    if (fits) {
        for (int i = t; i < c; i += 256) {
            unsigned int k = keys[st + i];
            kbuf[i] = k;
            atomicAdd(&hist[k >> 17], 1);
        }
    } else {  // statistically never for random edges; correct fallback via global scratch
        for (int i = t; i < c; i += 256) {
            unsigned int k = keys[st + i];
            scratch[st + i] = k;
            atomicAdd(&hist[k >> 17], 1);
        }
    }
    __syncthreads();
    if (t < 64) {  // wave 0: scan 64 counters
        int v = hist[t];
        int incl = v;
        for (int o = 1; o < 64; o <<= 1) {
            int other = __shfl_up(incl, o, 64);
            if (t >= o) incl += other;
        }
        int ex = incl - v;
        cur[t] = ex;
        int node = bk * BNODES + t;
        if (node < n) {
            rowstart[node] = st + ex;
            counts[node] = v;
            dinv[node] = rsqrtf((float)v + 1.0f);
        }
    }
    __syncthreads();
    if (fits) {
        for (int i = t; i < c; i += 256) {
            unsigned int k = kbuf[i];
            int pos = atomicAdd(&cur[k >> 17], 1);
            keys[st + pos] = k & 0x1FFFFu;
        }
    } else {
        for (int i = t; i < c; i += 256) {
            unsigned int k = scratch[st + i];
            int pos = atomicAdd(&cur[k >> 17], 1);
            keys[st + pos] = k & 0x1FFFFu;
        }
    }
}

// -------- GEMM1: h1b[n,64](bf16) = dinv * (x[n,64] @ W1[64,64]) --------
__global__ __launch_bounds__(256) void k_gemm1(const float* __restrict__ x,
                                               const float* __restrict__ W,
                                               const float* __restrict__ dinv,
                                               unsigned short* __restrict__ h) {
    __shared__ float Ws[64][64];
    __shared__ float xs[16][64];
    int t = threadIdx.x;
    for (int i = t; i < 64 * 64; i += 256) Ws[i >> 6][i & 63] = W[i];
    long long row0 = (long long)blockIdx.x * 16;
    ((float4*)xs)[t] = ((const float4*)(x + row0 * 64))[t];
    __syncthreads();
    int r = t >> 4, c0 = (t & 15) * 4;
    float4 acc = {0.f, 0.f, 0.f, 0.f};
#pragma unroll
    for (int k = 0; k < 64; ++k) {
        float xv = xs[r][k];
        float4 wv = *((const float4*)&Ws[k][c0]);
        acc.x += xv * wv.x; acc.y += xv * wv.y;
        acc.z += xv * wv.z; acc.w += xv * wv.w;
    }
    float di = dinv[row0 + r];
    ushort4 pk;
    pk.x = bf16enc(di * acc.x);
    pk.y = bf16enc(di * acc.y);
    pk.z = bf16enc(di * acc.z);
    pk.w = bf16enc(di * acc.w);
    *((ushort4*)(h + (row0 + r) * 64 + c0)) = pk;
}

// ------- CSR aggregation, 64 feats: ASYNC global_load_lds gather + FUSED GEMM2 -------
// One wave per node. Per batch of 8 edges, ONE global_load_lds instruction:
// lane l = (edge e8 = l>>3, chunk fq = l&7) loads 16B of row srcs[e8] to
// stage[wave][buf] + l*16 (wave-uniform LDS dest, per-lane global src).
// Data never touches VGPRs -> outstanding gathers aren't register-capped.
// Two buffers issued back-to-back = 16 edges in flight per wave.
__global__ __launch_bounds__(256) void k_agg64(const int* __restrict__ rowstart,
                                               const int* __restrict__ counts,
                                               const unsigned int* __restrict__ srcs,
                                               const unsigned short* __restrict__ h1b,
                                               const float* __restrict__ dinv,
                                               const float* __restrict__ b,
                                               const float* __restrict__ W2,
                                               unsigned short* __restrict__ h2b, int n) {
    __shared__ float W2s[64 * 17];                 // 4352 B
    __shared__ unsigned int stage[4][2][256];      // 4 waves x 2 bufs x 1KB = 8192 B
    int t = threadIdx.x;
    for (int i = t; i < 64 * 16; i += 256) W2s[(i >> 4) * 17 + (i & 15)] = W2[i];
    __syncthreads();  // before any divergence; all waves hit this immediately

    int d = (blockIdx.x * 256 + t) >> 6;
    if (d >= n) return;
    int w = t >> 6;
    int lane = t & 63;
    unsigned int half = lane >> 5;   // accumulate split: even/odd staged edges
    unsigned int fl = lane & 31;     // feature-pair index (features 2fl, 2fl+1)
    unsigned int e8 = lane >> 3;     // gather slot: edge-in-batch 0..7
    unsigned int fq = lane & 7;      // gather slot: 16B chunk 0..7
    const char* hb8 = (const char*)h1b;
    unsigned int* st0 = &stage[w][0][0];
    unsigned int* st1 = &stage[w][1][0];

    float ax = 0.f, ay = 0.f;
    if (half == 0) {                 // self-loop counted once
        unsigned int u = ((const unsigned int*)h1b)[(unsigned int)d * 32u + fl];
        ax = bf16lo(u); ay = bf16hi(u);
    }
    int start = rowstart[d];
    int cnt = counts[d];
    int k = 0;
    for (; k + 16 <= cnt; k += 16) {
        unsigned int seA = srcs[start + k + e8];
        unsigned int seB = srcs[start + k + 8 + e8];
        const void* gA = hb8 + (seA * 128u + fq * 16u);
        const void* gB = hb8 + (seB * 128u + fq * 16u);
        __builtin_amdgcn_global_load_lds(
            (const __attribute__((address_space(1))) void*)gA,
            (__attribute__((address_space(3))) void*)st0, 16, 0, 0);
        __builtin_amdgcn_global_load_lds(
            (const __attribute__((address_space(1))) void*)gB,
            (__attribute__((address_space(3))) void*)st1, 16, 0, 0);
        asm volatile("s_waitcnt vmcnt(0)" ::: "memory");
#pragma unroll
        for (int e = 0; e < 8; e += 2) {
            unsigned int u0 = st0[(e + half) * 32 + fl];
            unsigned int u1 = st1[(e + half) * 32 + fl];
            ax += bf16lo(u0); ay += bf16hi(u0);
            ax += bf16lo(u1); ay += bf16hi(u1);
        }
    }
    for (; k + 8 <= cnt; k += 8) {
        unsigned int seA = srcs[start + k + e8];
        const void* gA = hb8 + (seA * 128u + fq * 16u);
        __builtin_amdgcn_global_load_lds(
            (const __attribute__((address_space(1))) void*)gA,
            (__attribute__((address_space(3))) void*)st0, 16, 0, 0);
        asm volatile("s_waitcnt vmcnt(0)" ::: "memory");
#pragma unroll
        for (int e = 0; e < 8; e += 2) {
            unsigned int u0 = st0[(e + half) * 32 + fl];
            ax += bf16lo(u0); ay += bf16hi(u0);
        }
    }
    if (k < cnt) {                   // remainder 1..7 edges: clamp addr, mask accumulate
        int idx = k + (int)e8;
        unsigned int se = srcs[start + (idx < cnt ? idx : cnt - 1)];
        const void* gA = hb8 + (se * 128u + fq * 16u);
        __builtin_amdgcn_global_load_lds(
            (const __attribute__((address_space(1))) void*)gA,
            (__attribute__((address_space(3))) void*)st0, 16, 0, 0);
        asm volatile("s_waitcnt vmcnt(0)" ::: "memory");
        int rem = cnt - k;
#pragma unroll
        for (int e = 0; e < 8; e += 2) {
            if (e + (int)half < rem) {
                unsigned int u0 = st0[(e + half) * 32 + fl];
                ax += bf16lo(u0); ay += bf16hi(u0);
            }
        }
    }
    // combine even/odd halves; BOTH halves now hold row totals
    ax += __shfl_xor(ax, 32);
    ay += __shfl_xor(ay, 32);
    float di = dinv[d];
    float2 bb = ((const float2*)b)[fl];
    float ox = fmaxf(di * ax + bb.x, 0.f);   // relu'd feat 2fl
    float oy = fmaxf(di * ay + bb.y, 0.f);   // relu'd feat 2fl+1

    // fused GEMM2: lane computes partial dot for col c over its k-quarter
    int c = lane & 15, q = lane >> 4;
    float acc = 0.f;
#pragma unroll
    for (int j = 0; j < 16; ++j) {
        int kk = q * 16 + j;
        int srcl = kk >> 1;                       // lane holding feat kk
        float fv = (kk & 1) ? __shfl(oy, srcl) : __shfl(ox, srcl);
        acc += fv * W2s[kk * 17 + c];
    }
    acc += __shfl_xor(acc, 16);
    acc += __shfl_xor(acc, 32);
    if (lane < 16) h2b[(unsigned int)d * 16u + c] = bf16enc(di * acc);
}

// ------- CSR aggregation, 16 feats (bf16 h, scalar 8-unroll) + fused log_softmax ----
__global__ __launch_bounds__(256) void k_agg16(const int* __restrict__ rowstart,
                                               const int* __restrict__ counts,
                                               const unsigned int* __restrict__ srcs,
                                               const unsigned short* __restrict__ hb,
                                               const float* __restrict__ dinv,
                                               const float* __restrict__ b,
                                               float* __restrict__ out, int n) {
    int g = (blockIdx.x * 256 + threadIdx.x) >> 4;
    if (g >= n) return;
    unsigned int f = threadIdx.x & 15;
    float acc = bf16dec(hb[(unsigned int)g * 16u + f]);
    int start = rowstart[g];
    int cnt = counts[g];
    int k = 0;
    for (; k + 8 <= cnt; k += 8) {
        unsigned int s0 = srcs[start + k];
        unsigned int s1 = srcs[start + k + 1];
        unsigned int s2 = srcs[start + k + 2];
        unsigned int s3 = srcs[start + k + 3];
        unsigned int s4 = srcs[start + k + 4];
        unsigned int s5 = srcs[start + k + 5];
        unsigned int s6 = srcs[start + k + 6];
        unsigned int s7 = srcs[start + k + 7];
        unsigned short u0 = hb[s0 * 16u + f];
        unsigned short u1 = hb[s1 * 16u + f];
        unsigned short u2 = hb[s2 * 16u + f];
        unsigned short u3 = hb[s3 * 16u + f];
        unsigned short u4 = hb[s4 * 16u + f];
        unsigned short u5 = hb[s5 * 16u + f];
        unsigned short u6 = hb[s6 * 16u + f];
        unsigned short u7 = hb[s7 * 16u + f];
        acc += bf16dec(u0); acc += bf16dec(u1); acc += bf16dec(u2); acc += bf16dec(u3);
        acc += bf16dec(u4); acc += bf16dec(u5); acc += bf16dec(u6); acc += bf16dec(u7);
    }
    for (; k < cnt; ++k) acc += bf16dec(hb[srcs[start + k] * 16u + f]);
    float v = dinv[g] * acc + b[f];
    float m = v;
#pragma unroll
    for (int o = 8; o >= 1; o >>= 1) m = fmaxf(m, __shfl_xor(m, o, 16));
    float ex = __expf(v - m);
#pragma unroll
    for (int o = 8; o >= 1; o >>= 1) ex += __shfl_xor(ex, o, 16);
    out[(unsigned int)g * 16u + f] = (v - m) - __logf(ex);
}

extern "C" void kernel_launch(void* const* d_in, const int* in_sizes, int n_in,
                              void* d_out, int out_size, void* d_ws, size_t ws_size,
                              hipStream_t stream) {
    const float* x  = (const float*)d_in[0];
    const void*  ei = d_in[1];
    const float* W1 = (const float*)d_in[2];
    const float* b1 = (const float*)d_in[3];
    const float* W2 = (const float*)d_in[4];
    const float* b2 = (const float*)d_in[5];

    long long dh  = in_sizes[3];                 // 64
    long long din = in_sizes[2] / dh;            // 64
    long long n   = in_sizes[0] / din;           // 50000
    long long E   = (long long)in_sizes[1] / 2;  // 1.6M
    int nbuckets  = (int)((n + BNODES - 1) >> BSHIFT);  // 782

    // slice size: 512 threads x ~16 edges; keep block count <= 256 (k_scanB width)
    long long epb = 8192;
    while ((E + epb - 1) / epb > 256) epb <<= 1;
    int nblk = (int)((E + epb - 1) / epb);       // 196 for E=1.6M

    char* ws = (char*)d_ws;
    auto alloc = [&](size_t bytes) { void* p = ws; ws += (bytes + 255) & ~255ULL; return p; };
    int*   totals   = (int*)alloc(nbuckets * 4);
    int*   base     = (int*)alloc(nbuckets * 4);
    int*   rowstart = (int*)alloc(n * 4);
    int*   counts   = (int*)alloc(n * 4);
    float* dinv     = (float*)alloc(n * 4);
    int*   partial  = (int*)alloc((size_t)nbuckets * nblk * 4);
    unsigned int* keys = (unsigned int*)alloc(E * 4);
    unsigned short* h1b  = (unsigned short*)alloc(n * 64 * 2);
    unsigned short* h2b  = (unsigned short*)alloc(n * 16 * 2);
    // h1b is written only after sortdeg completes; before then its space doubles
    // as the (statistically never used) big-bucket sort scratch (E*4 <= n*64*2).
    unsigned int* sort_scratch = (unsigned int*)h1b;

    float* out = (float*)d_out;

    // binning: hist -> per-bucket block scan -> bucket scan -> place (no global atomics)
    k_hist<<<nblk, 512, 0, stream>>>(ei, n, E, epb, nbuckets, nblk, partial);
    k_scanB<<<nbuckets, 256, 0, stream>>>(partial, nblk, totals);
    k_scan<<<1, 1024, 0, stream>>>(totals, nbuckets, base);
    k_place<<<nblk, 512, 0, stream>>>(ei, n, E, epb, nbuckets, nblk, base, partial, keys);
    k_sortdeg<<<nbuckets, 256, 0, stream>>>(keys, base, totals, rowstart, counts,
                                            dinv, (int)n, sort_scratch);

    // layer 1 (+ fused layer-2 GEMM in agg64 epilogue)
    k_gemm1<<<(int)(n / 16), 256, 0, stream>>>(x, W1, dinv, h1b);
    k_agg64<<<(int)((n * 64 + 255) / 256), 256, 0, stream>>>(
        rowstart, counts, keys, h1b, dinv, b1, W2, h2b, (int)n);

    // layer 2 aggregation + log_softmax
    k_agg16<<<(int)((n * 16 + 255) / 256), 256, 0, stream>>>(
        rowstart, counts, keys, h2b, dinv, b2, out, (int)n);
}

// Round 17
// 110.387 us; speedup vs baseline: 1.0806x; 1.0370x over previous
//
#include <hip/hip_runtime.h>
#include <hip/hip_bf16.h>
#include <math.h>

// bucket = 64 consecutive dst nodes. key packs (dlow<<17 | src), valid for n < 131072.
#define BSHIFT 6
#define BNODES 64
#define MAXB 1024   // max buckets supported by single-block scan (n <= 65536)
#define SORTCAP 4096

// ---------------- inline dtype detection: int64 vs int32 edge_index ----------------
__device__ __forceinline__ bool detect_f64(const void* edges, long long nn) {
    const long long* e64 = (const long long*)edges;
    bool ok = true;
#pragma unroll
    for (int i = 0; i < 8; ++i) {
        long long v = e64[i];
        ok = ok && (v >= 0 && v < nn);
    }
    return ok;
}

__device__ __forceinline__ float bf16lo(unsigned int u) {
    return __uint_as_float(u << 16);
}
__device__ __forceinline__ float bf16hi(unsigned int u) {
    return __uint_as_float(u & 0xFFFF0000u);
}
__device__ __forceinline__ float bf16dec(unsigned short u) {
    return __uint_as_float(((unsigned int)u) << 16);
}
__device__ __forceinline__ unsigned short bf16enc(float f) {
    __hip_bfloat16 h = __float2bfloat16(f);
    return *reinterpret_cast<unsigned short*>(&h);
}

// ---- (A) FAT kernel: blocks [0,nblk) = per-slice histogram; rest = GEMM1 ----
// hist: LDS histogram of dst buckets -> partial[b*nblk+i] (plain stores).
// gemm1: h1b[n,64](bf16) = x[n,64] @ W1[64,64]  (UNSCALED; dinv folded into agg64)
// Independent work overlapped in one launch.
__global__ __launch_bounds__(256) void k_hist_gemm1(const void* edges, long long nn,
                                                    long long E, long long epb,
                                                    int nbuckets, int nblk, int* partial,
                                                    const float* __restrict__ x,
                                                    const float* __restrict__ W1,
                                                    unsigned short* __restrict__ h1b) {
    __shared__ __align__(16) char smem[20480];   // hist: 4KB cnt | gemm1: 16KB Ws + 4KB xs
    int t = threadIdx.x;
    if (blockIdx.x < (unsigned int)nblk) {
        int* cnt = (int*)smem;
        int i = blockIdx.x;
        for (int b = t; b < nbuckets; b += 256) cnt[b] = 0;
        __syncthreads();
        bool f64 = detect_f64(edges, nn);
        long long e0 = (long long)i * epb;
        long long e1 = e0 + epb; if (e1 > E) e1 = E;
        for (long long e = e0 + t; e < e1; e += 256) {
            int d = f64 ? (int)((const long long*)edges)[E + e] : ((const int*)edges)[E + e];
            atomicAdd(&cnt[d >> BSHIFT], 1);
        }
        __syncthreads();
        for (int b = t; b < nbuckets; b += 256) partial[b * nblk + i] = cnt[b];
    } else {
        float (*Ws)[64] = (float(*)[64])smem;
        float (*xs)[64] = (float(*)[64])(smem + 64 * 64 * 4);
        for (int i = t; i < 64 * 64; i += 256) Ws[i >> 6][i & 63] = W1[i];
        long long row0 = (long long)(blockIdx.x - nblk) * 16;
        ((float4*)xs)[t] = ((const float4*)(x + row0 * 64))[t];
        __syncthreads();
        int r = t >> 4, c0 = (t & 15) * 4;
        float4 acc = {0.f, 0.f, 0.f, 0.f};
#pragma unroll
        for (int k = 0; k < 64; ++k) {
            float xv = xs[r][k];
            float4 wv = *((const float4*)&Ws[k][c0]);
            acc.x += xv * wv.x; acc.y += xv * wv.y;
            acc.z += xv * wv.z; acc.w += xv * wv.w;
        }
        ushort4 pk;
        pk.x = bf16enc(acc.x);
        pk.y = bf16enc(acc.y);
        pk.z = bf16enc(acc.z);
        pk.w = bf16enc(acc.w);
        *((ushort4*)(h1b + (row0 + r) * 64 + c0)) = pk;
    }
}

// ---- (B) per-bucket exclusive scan over blocks; emits bucket totals ----
__global__ __launch_bounds__(256) void k_scanB(int* partial, int nblk, int* totals) {
    __shared__ int tmp[256];
    int b = blockIdx.x, t = threadIdx.x;
    int v = (t < nblk) ? partial[b * nblk + t] : 0;
    tmp[t] = v;
    __syncthreads();
    for (int off = 1; off < 256; off <<= 1) {
        int a = (t >= off) ? tmp[t - off] : 0;
        __syncthreads();
        tmp[t] += a;
        __syncthreads();
    }
    if (t < nblk) partial[b * nblk + t] = tmp[t] - v;  // exclusive over blocks
    if (t == 255) totals[b] = tmp[255];
}

// ---- (C) bucket-level exclusive scan: base = exclusive(totals) ----
__global__ __launch_bounds__(1024) void k_scan(const int* __restrict__ totals, int nbuckets,
                                               int* base) {
    __shared__ int tmp[MAXB];
    int t = threadIdx.x;
    int v = (t < nbuckets) ? totals[t] : 0;
    tmp[t] = v;
    __syncthreads();
    for (int off = 1; off < MAXB; off <<= 1) {
        int a = (t >= off) ? tmp[t - off] : 0;
        __syncthreads();
        tmp[t] += a;
        __syncthreads();
    }
    if (t < nbuckets) base[t] = tmp[t] - v;
}

// ---- (D) place keys: LDS cursors seeded from base+partial; no global atomics ----
__global__ __launch_bounds__(512) void k_place(const void* edges, long long nn,
                                               long long E, long long epb,
                                               int nbuckets, int nblk,
                                               const int* __restrict__ base,
                                               const int* __restrict__ partial,
                                               unsigned int* keys) {
    __shared__ int cur[MAXB];
    int t = threadIdx.x;
    int i = blockIdx.x;
    for (int b = t; b < nbuckets; b += 512) cur[b] = base[b] + partial[b * nblk + i];
    __syncthreads();
    bool f64 = detect_f64(edges, nn);
    long long e0 = (long long)i * epb;
    long long e1 = e0 + epb; if (e1 > E) e1 = E;
    for (long long e = e0 + t; e < e1; e += 512) {
        int s, d;
        if (f64) {
            const long long* ee = (const long long*)edges;
            s = (int)ee[e]; d = (int)ee[E + e];
        } else {
            const int* ee = (const int*)edges;
            s = ee[e]; d = ee[E + e];
        }
        int pos = atomicAdd(&cur[d >> BSHIFT], 1);
        keys[pos] = (unsigned int)s | ((unsigned int)(d & (BNODES - 1)) << 17);
    }
}

// -------- per-bucket LDS counting sort -> node-exact CSR; fuses deg/dinv --------
__global__ __launch_bounds__(256) void k_sortdeg(unsigned int* keys,
                                                 const int* __restrict__ base,
                                                 const int* __restrict__ totals,
                                                 int* rowstart, int* counts,
                                                 float* dinv, int n,
                                                 unsigned int* scratch) {
    __shared__ unsigned int kbuf[SORTCAP];
    __shared__ int hist[BNODES];
    __shared__ int cur[BNODES];
    int t = threadIdx.x;
    int bk = blockIdx.x;
    int st = base[bk], c = totals[bk];
    if (t < BNODES) hist[t] = 0;
    __syncthreads();
    bool fits = (c <= SORTCAP);
    if (fits) {
        for (int i = t; i < c; i += 256) {
            unsigned int k = keys[st + i];
            kbuf[i] = k;
            atomicAdd(&hist[k >> 17], 1);
        }
    } else {  // statistically never for random edges; correct fallback via global scratch
        for (int i = t; i < c; i += 256) {
            unsigned int k = keys[st + i];
            scratch[st + i] = k;
            atomicAdd(&hist[k >> 17], 1);
        }
    }
    __syncthreads();
    if (t < 64) {  // wave 0: scan 64 counters
        int v = hist[t];
        int incl = v;
        for (int o = 1; o < 64; o <<= 1) {
            int other = __shfl_up(incl, o, 64);
            if (t >= o) incl += other;
        }
        int ex = incl - v;
        cur[t] = ex;
        int node = bk * BNODES + t;
        if (node < n) {
            rowstart[node] = st + ex;
            counts[node] = v;
            dinv[node] = rsqrtf((float)v + 1.0f);
        }
    }
    __syncthreads();
    if (fits) {
        for (int i = t; i < c; i += 256) {
            unsigned int k = kbuf[i];
            int pos = atomicAdd(&cur[k >> 17], 1);
            keys[st + pos] = k & 0x1FFFFu;
        }
    } else {
        for (int i = t; i < c; i += 256) {
            unsigned int k = scratch[st + i];
            int pos = atomicAdd(&cur[k >> 17], 1);
            keys[st + pos] = k & 0x1FFFFu;
        }
    }
}

// ------- CSR aggregation, 64 feats (bf16, 4-wide, dinv-FMA) + FUSED GEMM2 -------
// h1b is UNSCALED; per edge multiply by dinv[s] (broadcast load, fma replaces add).
// 16 lanes x uint2 (8B) cover a 128B row; quarter-waves process edges k+0..k+3.
__global__ __launch_bounds__(256) void k_agg64(const int* __restrict__ rowstart,
                                               const int* __restrict__ counts,
                                               const unsigned int* __restrict__ srcs,
                                               const uint2* __restrict__ hb4,
                                               const float* __restrict__ dinv,
                                               const float* __restrict__ b,
                                               const float* __restrict__ W2,
                                               unsigned short* __restrict__ h2b, int n) {
    __shared__ float W2s[64 * 17];
    int t = threadIdx.x;
    for (int i = t; i < 64 * 16; i += 256) W2s[(i >> 4) * 17 + (i & 15)] = W2[i];
    __syncthreads();  // before any divergence; all waves hit this immediately

    int d = (blockIdx.x * 256 + t) >> 6;
    if (d >= n) return;
    int lane = t & 63;
    unsigned int q = lane >> 4;      // quarter: edge offset 0..3
    unsigned int fl = lane & 15;     // feature-quad index (feats 4fl..4fl+3)
    float di = dinv[d];
    float a0 = 0.f, a1 = 0.f, a2 = 0.f, a3 = 0.f;
    if (q == 0) {                    // self-loop: dinv[d] * h1[d]
        uint2 u = hb4[(unsigned int)d * 16u + fl];
        a0 = di * bf16lo(u.x); a1 = di * bf16hi(u.x);
        a2 = di * bf16lo(u.y); a3 = di * bf16hi(u.y);
    }
    int start = rowstart[d];
    int cnt = counts[d];
    int k = 0;
    for (; k + 16 <= cnt; k += 16) {
        unsigned int s0 = srcs[start + k + q];
        unsigned int s1 = srcs[start + k + 4 + q];
        unsigned int s2 = srcs[start + k + 8 + q];
        unsigned int s3 = srcs[start + k + 12 + q];
        float dv0 = dinv[s0];
        float dv1 = dinv[s1];
        float dv2 = dinv[s2];
        float dv3 = dinv[s3];
        uint2 u0 = hb4[s0 * 16u + fl];
        uint2 u1 = hb4[s1 * 16u + fl];
        uint2 u2 = hb4[s2 * 16u + fl];
        uint2 u3 = hb4[s3 * 16u + fl];
        a0 = fmaf(dv0, bf16lo(u0.x), a0); a1 = fmaf(dv0, bf16hi(u0.x), a1);
        a2 = fmaf(dv0, bf16lo(u0.y), a2); a3 = fmaf(dv0, bf16hi(u0.y), a3);
        a0 = fmaf(dv1, bf16lo(u1.x), a0); a1 = fmaf(dv1, bf16hi(u1.x), a1);
        a2 = fmaf(dv1, bf16lo(u1.y), a2); a3 = fmaf(dv1, bf16hi(u1.y), a3);
        a0 = fmaf(dv2, bf16lo(u2.x), a0); a1 = fmaf(dv2, bf16hi(u2.x), a1);
        a2 = fmaf(dv2, bf16lo(u2.y), a2); a3 = fmaf(dv2, bf16hi(u2.y), a3);
        a0 = fmaf(dv3, bf16lo(u3.x), a0); a1 = fmaf(dv3, bf16hi(u3.x), a1);
        a2 = fmaf(dv3, bf16lo(u3.y), a2); a3 = fmaf(dv3, bf16hi(u3.y), a3);
    }
    for (; k + 8 <= cnt; k += 8) {
        unsigned int s0 = srcs[start + k + q];
        unsigned int s1 = srcs[start + k + 4 + q];
        float dv0 = dinv[s0];
        float dv1 = dinv[s1];
        uint2 u0 = hb4[s0 * 16u + fl];
        uint2 u1 = hb4[s1 * 16u + fl];
        a0 = fmaf(dv0, bf16lo(u0.x), a0); a1 = fmaf(dv0, bf16hi(u0.x), a1);
        a2 = fmaf(dv0, bf16lo(u0.y), a2); a3 = fmaf(dv0, bf16hi(u0.y), a3);
        a0 = fmaf(dv1, bf16lo(u1.x), a0); a1 = fmaf(dv1, bf16hi(u1.x), a1);
        a2 = fmaf(dv1, bf16lo(u1.y), a2); a3 = fmaf(dv1, bf16hi(u1.y), a3);
    }
    for (; k < cnt; k += 4) {
        int idx = k + (int)q;
        if (idx < cnt) {
            unsigned int s0 = srcs[start + idx];
            float dv0 = dinv[s0];
            uint2 u0 = hb4[s0 * 16u + fl];
            a0 = fmaf(dv0, bf16lo(u0.x), a0); a1 = fmaf(dv0, bf16hi(u0.x), a1);
            a2 = fmaf(dv0, bf16lo(u0.y), a2); a3 = fmaf(dv0, bf16hi(u0.y), a3);
        }
    }
    // combine quarters (lanes with equal fl: xor 16, 32); all lanes hold totals
    a0 += __shfl_xor(a0, 16); a0 += __shfl_xor(a0, 32);
    a1 += __shfl_xor(a1, 16); a1 += __shfl_xor(a1, 32);
    a2 += __shfl_xor(a2, 16); a2 += __shfl_xor(a2, 32);
    a3 += __shfl_xor(a3, 16); a3 += __shfl_xor(a3, 32);
    float4 bb = ((const float4*)b)[fl];
    float o0 = fmaxf(di * a0 + bb.x, 0.f);   // relu'd feat 4fl+0
    float o1 = fmaxf(di * a1 + bb.y, 0.f);
    float o2 = fmaxf(di * a2 + bb.z, 0.f);
    float o3 = fmaxf(di * a3 + bb.w, 0.f);

    // fused GEMM2: lane computes partial dot for col c over its quarter's 16 feats
    int c = lane & 15;
    float acc = 0.f;
#pragma unroll
    for (int j = 0; j < 16; ++j) {
        int kk = (int)q * 16 + j;            // feat index this lane consumes
        int srcl = (int)q * 20 + (j >> 2);   // q*16 + (kk>>2): holder within quarter
        float fv;
        if ((j & 3) == 0)      fv = __shfl(o0, srcl);
        else if ((j & 3) == 1) fv = __shfl(o1, srcl);
        else if ((j & 3) == 2) fv = __shfl(o2, srcl);
        else                   fv = __shfl(o3, srcl);
        acc += fv * W2s[kk * 17 + c];
    }
    acc += __shfl_xor(acc, 16);
    acc += __shfl_xor(acc, 32);
    if (lane < 16) h2b[(unsigned int)d * 16u + c] = bf16enc(di * acc);
}

// ------- CSR aggregation, 16 feats (bf16 h, scalar 8-unroll) + fused log_softmax ----
__global__ __launch_bounds__(256) void k_agg16(const int* __restrict__ rowstart,
                                               const int* __restrict__ counts,
                                               const unsigned int* __restrict__ srcs,
                                               const unsigned short* __restrict__ hb,
                                               const float* __restrict__ dinv,
                                               const float* __restrict__ b,
                                               float* __restrict__ out, int n) {
    int g = (blockIdx.x * 256 + threadIdx.x) >> 4;
    if (g >= n) return;
    unsigned int f = threadIdx.x & 15;
    float acc = bf16dec(hb[(unsigned int)g * 16u + f]);
    int start = rowstart[g];
    int cnt = counts[g];
    int k = 0;
    for (; k + 8 <= cnt; k += 8) {
        unsigned int s0 = srcs[start + k];
        unsigned int s1 = srcs[start + k + 1];
        unsigned int s2 = srcs[start + k + 2];
        unsigned int s3 = srcs[start + k + 3];
        unsigned int s4 = srcs[start + k + 4];
        unsigned int s5 = srcs[start + k + 5];
        unsigned int s6 = srcs[start + k + 6];
        unsigned int s7 = srcs[start + k + 7];
        unsigned short u0 = hb[s0 * 16u + f];
        unsigned short u1 = hb[s1 * 16u + f];
        unsigned short u2 = hb[s2 * 16u + f];
        unsigned short u3 = hb[s3 * 16u + f];
        unsigned short u4 = hb[s4 * 16u + f];
        unsigned short u5 = hb[s5 * 16u + f];
        unsigned short u6 = hb[s6 * 16u + f];
        unsigned short u7 = hb[s7 * 16u + f];
        acc += bf16dec(u0); acc += bf16dec(u1); acc += bf16dec(u2); acc += bf16dec(u3);
        acc += bf16dec(u4); acc += bf16dec(u5); acc += bf16dec(u6); acc += bf16dec(u7);
    }
    for (; k < cnt; ++k) acc += bf16dec(hb[srcs[start + k] * 16u + f]);
    float v = dinv[g] * acc + b[f];
    float m = v;
#pragma unroll
    for (int o = 8; o >= 1; o >>= 1) m = fmaxf(m, __shfl_xor(m, o, 16));
    float ex = __expf(v - m);
#pragma unroll
    for (int o = 8; o >= 1; o >>= 1) ex += __shfl_xor(ex, o, 16);
    out[(unsigned int)g * 16u + f] = (v - m) - __logf(ex);
}

extern "C" void kernel_launch(void* const* d_in, const int* in_sizes, int n_in,
                              void* d_out, int out_size, void* d_ws, size_t ws_size,
                              hipStream_t stream) {
    const float* x  = (const float*)d_in[0];
    const void*  ei = d_in[1];
    const float* W1 = (const float*)d_in[2];
    const float* b1 = (const float*)d_in[3];
    const float* W2 = (const float*)d_in[4];
    const float* b2 = (const float*)d_in[5];

    long long dh  = in_sizes[3];                 // 64
    long long din = in_sizes[2] / dh;            // 64
    long long n   = in_sizes[0] / din;           // 50000
    long long E   = (long long)in_sizes[1] / 2;  // 1.6M
    int nbuckets  = (int)((n + BNODES - 1) >> BSHIFT);  // 782

    // slice size: keep block count <= 256 (k_scanB width)
    long long epb = 8192;
    while ((E + epb - 1) / epb > 256) epb <<= 1;
    int nblk = (int)((E + epb - 1) / epb);       // 196 for E=1.6M
    int ngemm = (int)(n / 16);                   // 3125 gemm1 blocks

    char* ws = (char*)d_ws;
    auto alloc = [&](size_t bytes) { void* p = ws; ws += (bytes + 255) & ~255ULL; return p; };
    int*   totals   = (int*)alloc(nbuckets * 4);
    int*   base     = (int*)alloc(nbuckets * 4);
    int*   rowstart = (int*)alloc(n * 4);
    int*   counts   = (int*)alloc(n * 4);
    float* dinv     = (float*)alloc(n * 4);
    int*   partial  = (int*)alloc((size_t)nbuckets * nblk * 4);
    unsigned int* keys = (unsigned int*)alloc(E * 4);
    unsigned short* h1b  = (unsigned short*)alloc(n * 64 * 2);
    unsigned short* h2b  = (unsigned short*)alloc(n * 16 * 2);
    // sortdeg's big-bucket fallback scratch (statistically never used): h2b is
    // not written until agg64, well after sortdeg; but it is only 1.6MB < E*4.
    // Use a dedicated region instead.
    unsigned int* sort_scratch = (unsigned int*)alloc(E * 4);

    float* out = (float*)d_out;

    // fat launch: hist (blocks 0..nblk) overlapped with gemm1 (rest)
    k_hist_gemm1<<<nblk + ngemm, 256, 0, stream>>>(ei, n, E, epb, nbuckets, nblk,
                                                   partial, x, W1, h1b);
    k_scanB<<<nbuckets, 256, 0, stream>>>(partial, nblk, totals);
    k_scan<<<1, 1024, 0, stream>>>(totals, nbuckets, base);
    k_place<<<nblk, 512, 0, stream>>>(ei, n, E, epb, nbuckets, nblk, base, partial, keys);
    k_sortdeg<<<nbuckets, 256, 0, stream>>>(keys, base, totals, rowstart, counts,
                                            dinv, (int)n, sort_scratch);

    // layer 1 aggregation (+ fused layer-2 GEMM in epilogue)
    k_agg64<<<(int)((n * 64 + 255) / 256), 256, 0, stream>>>(
        rowstart, counts, keys, (const uint2*)h1b, dinv, b1, W2, h2b, (int)n);

    // layer 2 aggregation + log_softmax
    k_agg16<<<(int)((n * 16 + 255) / 256), 256, 0, stream>>>(
        rowstart, counts, keys, h2b, dinv, b2, out, (int)n);
}